// Round 18
// baseline (245.419 us; speedup 1.0000x reference)
//
#include <hip/hip_runtime.h>
#include <stdint.h>

#define NB 4
#define NS 2048
#define NE 1024
#define NH 16
#define ND 64

typedef __attribute__((ext_vector_type(8))) short short8;
typedef __attribute__((ext_vector_type(2))) float f32x2;
typedef __attribute__((ext_vector_type(4))) float f32x4;
typedef __attribute__((ext_vector_type(8))) float f32x8;
typedef __attribute__((ext_vector_type(16))) float f32x16;
typedef __attribute__((ext_vector_type(4))) unsigned short us4;
typedef __attribute__((ext_vector_type(4))) unsigned int u32x4;
typedef __attribute__((ext_vector_type(2))) __bf16 bf16x2;

#define LOG2E 1.4426950408889634f

// f32 -> bf16 RNE via native cast (clang emits v_cvt_pk_bf16_f32 pairs).
__device__ __forceinline__ unsigned short f2bf(float f) {
    return __builtin_bit_cast(unsigned short, static_cast<__bf16>(f));
}
__device__ __forceinline__ unsigned int packbf(float lo, float hi_) {
    f32x2 v; v[0] = lo; v[1] = hi_;
    return __builtin_bit_cast(unsigned int, __builtin_convertvector(v, bf16x2));
}
// native v_exp_f32 (2^x) - avoids OCML exp2f's denormal-fixup sequence
__device__ __forceinline__ float exp2n(float x) {
    float y;
    asm("v_exp_f32 %0, %1" : "=v"(y) : "v"(x));
    return y;
}
// async global->LDS, 16B per lane (LDS dest = wave-uniform base + lane*16)
__device__ __forceinline__ void gl_lds16(const void* g, void* l) {
    __builtin_amdgcn_global_load_lds(
        (const __attribute__((address_space(1))) unsigned int*)g,
        (__attribute__((address_space(3))) unsigned int*)l, 16, 0, 0);
}

// ---------------- weight fp32 -> bf16 (weights only), one launch ----------------
// Wq (g==2) pre-scaled by log2e so attention logits arrive in exp2 domain.
__global__ __launch_bounds__(256) void cvt_w4_kernel(const float* __restrict__ w0,
                                                     const float* __restrict__ w1,
                                                     const float* __restrict__ w2,
                                                     const float* __restrict__ w3,
                                                     unsigned short* __restrict__ d0,
                                                     unsigned short* __restrict__ d1,
                                                     unsigned short* __restrict__ d2,
                                                     unsigned short* __restrict__ d3) {
    const int g = blockIdx.x >> 10;            // which weight (1024 blocks each)
    const float* src = g == 0 ? w0 : g == 1 ? w1 : g == 2 ? w2 : w3;
    unsigned short* dst = g == 0 ? d0 : g == 1 ? d1 : g == 2 ? d2 : d3;
    const float scl = (g == 2) ? LOG2E : 1.0f;
    const int i = ((blockIdx.x & 1023) * 256 + threadIdx.x) * 4;
    f32x4 f = *(const f32x4*)(src + i);
    us4 o;
#pragma unroll
    for (int j = 0; j < 4; ++j) o[j] = f2bf(f[j] * scl);
    *(us4*)(dst + i) = o;
}

// ---------------- hybrid QKV GEMM: C = A_f32 @ W_bf16^T ----------------
// A fp32 [M,1024] converted to bf16 in-register during staging (pad-36 LDS: stride
// 72B = 18 banks, gcd(18,32)=2 -> ~4-way writes / ~2-way reads); W bf16 via
// global_load_lds (linear dbuf). Per iter: LOAD_A(t+1) FIRST (oldest outstanding,
// so WRITE_A waits vmcnt(2) = A only), then W gloads(t+1); compute(t); convert+
// ds_write A(t+1); barrier. Grid is bn-FASTEST so the 8 blocks sharing an A tile
// are dispatch-adjacent (A re-reads hit L2, not L3).
// z=0,1 -> bf16 [B,H,S,D]; z==2 -> V^T kv-blocked [B,H,S/64,D,64].
struct HybArgs {
    const float *a0, *a1, *a2;
    const unsigned short *w0, *w1, *w2;
    void *c0, *c1, *c2;
};

__global__ __launch_bounds__(256) void gemm_hyb(HybArgs args) {
    __shared__ unsigned short As[2][128][36];             // pad 36: 2-way-ish pattern
    __shared__ __align__(16) unsigned short Bs[2][4096];  // linear, gload_lds dest
    const int tid = threadIdx.x;
    const int bn = blockIdx.x, bm = blockIdx.y, z = blockIdx.z;   // bn fastest!
    const float* Ab          = z == 0 ? args.a0 : z == 1 ? args.a1 : args.a2;
    const unsigned short* Wb = z == 0 ? args.w0 : z == 1 ? args.w1 : args.w2;
    void* Cp                 = z == 0 ? args.c0 : z == 1 ? args.c1 : args.c2;
    const int lane = tid & 63, wid = tid >> 6;
    const int lr = lane & 15, lg = lane >> 4;
    const int wr = wid >> 1, wc = wid & 1;
    const int srow = tid >> 1, shalf = tid & 1;

    const float* apF = Ab + (size_t)(bm * 128 + srow) * 1024 + shalf * 16;
    const size_t boff = (size_t)(bn * 128 + (tid >> 2)) * 1024 + (tid & 3) * 8;

    f32x4 acc[4][4];
#pragma unroll
    for (int a = 0; a < 4; ++a)
#pragma unroll
        for (int b = 0; b < 4; ++b) acc[a][b] = (f32x4){0.f, 0.f, 0.f, 0.f};

#define STAGE_W(buf, kk) { \
    gl_lds16(Wb + boff + (kk),             &Bs[buf][tid * 8]); \
    gl_lds16(Wb + boff + 64 * 1024 + (kk), &Bs[buf][2048 + tid * 8]); }
#define LOAD_A(kk) { \
    pa0 = *(const f32x4*)(apF + (kk)); \
    pa1 = *(const f32x4*)(apF + (kk) + 4); \
    pa2 = *(const f32x4*)(apF + (kk) + 8); \
    pa3 = *(const f32x4*)(apF + (kk) + 12); }
#define WRITE_A(buf) { \
    short8 p0, p1; \
    for (int j = 0; j < 4; ++j) { \
        p0[j] = (short)f2bf(pa0[j]); p0[j + 4] = (short)f2bf(pa1[j]); \
        p1[j] = (short)f2bf(pa2[j]); p1[j + 4] = (short)f2bf(pa3[j]); } \
    *(short8*)&As[buf][srow][shalf * 16]     = p0; \
    *(short8*)&As[buf][srow][shalf * 16 + 8] = p1; }

    f32x4 pa0, pa1, pa2, pa3;
    LOAD_A(0)
    STAGE_W(0, 0)
    WRITE_A(0)
    __syncthreads();   // W tile 0 drained (vmcnt 0), A writes visible
    int cur = 0;
    for (int k0 = 0; k0 < 1024; k0 += 32) {
        const int last = (k0 + 32 >= 1024);
        if (!last) {
            LOAD_A(k0 + 32)             // issue A first: oldest outstanding VMEM
            STAGE_W(cur ^ 1, k0 + 32)   // W gloads fly under compute + WRITE_A
        }
        short8 af[4], bfr[4];
#pragma unroll
        for (int mi = 0; mi < 4; ++mi)
            af[mi] = *(const short8*)&As[cur][wr * 64 + mi * 16 + lr][lg * 8];
#pragma unroll
        for (int ni = 0; ni < 4; ++ni)
            bfr[ni] = *(const short8*)&Bs[cur][(wc * 64 + ni * 16 + lr) * 32 + lg * 8];
#pragma unroll
        for (int mi = 0; mi < 4; ++mi)
#pragma unroll
            for (int ni = 0; ni < 4; ++ni)
                acc[mi][ni] = __builtin_amdgcn_mfma_f32_16x16x32_bf16(af[mi], bfr[ni], acc[mi][ni], 0, 0, 0);
        if (!last) WRITE_A(cur ^ 1)     // waits only A loads (vmcnt 2), overlaps W
        __syncthreads();                // drains W loads + A writes visible
        cur ^= 1;
    }
#undef STAGE_W
#undef LOAD_A
#undef WRITE_A

#pragma unroll
    for (int mi = 0; mi < 4; ++mi) {
#pragma unroll
        for (int ni = 0; ni < 4; ++ni) {
            const int n = bn * 128 + wc * 64 + ni * 16 + lr;
            if (z == 2) {
                // V^T kv-blocked: [B,H,S/64,D,64]; i -> s consecutive within a 64-block.
                const int m0 = bm * 128 + wr * 64 + mi * 16 + lg * 4;
                const int b = m0 >> 11, s0 = m0 & 2047;
                const int h = n >> 6, d = n & 63;
                us4 pk;
#pragma unroll
                for (int i = 0; i < 4; ++i) pk[i] = f2bf(acc[mi][ni][i]);
                const size_t idx = ((((size_t)b * NH + h) * (NS / 64) + (s0 >> 6)) * ND + d) * 64 + (s0 & 63);
                *(us4*)&((unsigned short*)Cp)[idx] = pk;
            } else {
#pragma unroll
                for (int i = 0; i < 4; ++i) {
                    const int m = bm * 128 + wr * 64 + mi * 16 + lg * 4 + i;
                    const int b = m >> 11, s = m & 2047, h = n >> 6, d = n & 63;
                    ((unsigned short*)Cp)[(((size_t)b * NH + h) * NS + s) * ND + d] = f2bf(acc[mi][ni][i]);
                }
            }
        }
    }
}

// ---------------- epilogue GEMM via global_load_lds: fp32 C = A_bf16 @ W^T + bias ----------------
__global__ __launch_bounds__(256) void gemm_glds(const unsigned short* __restrict__ Ab,
                                                 const unsigned short* __restrict__ Wb,
                                                 float* __restrict__ Cp,
                                                 const float* __restrict__ bias) {
    __shared__ __align__(16) unsigned short As[2][4096];
    __shared__ __align__(16) unsigned short Bs[2][4096];
    const int tid = threadIdx.x;
    const int bn = blockIdx.x, bm = blockIdx.y;   // bn fastest (A-tile sharing in L2)
    const int lane = tid & 63, wid = tid >> 6;
    const int lr = lane & 15, lg = lane >> 4;
    const int wr = wid >> 1, wc = wid & 1;

    const size_t aoff = (size_t)(bm * 128 + (tid >> 2)) * 1024 + (tid & 3) * 8;
    const size_t boff = (size_t)(bn * 128 + (tid >> 2)) * 1024 + (tid & 3) * 8;

    f32x4 acc[4][4];
#pragma unroll
    for (int a = 0; a < 4; ++a)
#pragma unroll
        for (int b = 0; b < 4; ++b) acc[a][b] = (f32x4){0.f, 0.f, 0.f, 0.f};

#define STAGE(buf, kk) { \
    gl_lds16(Ab + aoff + (kk),             &As[buf][tid * 8]); \
    gl_lds16(Ab + aoff + 64 * 1024 + (kk), &As[buf][2048 + tid * 8]); \
    gl_lds16(Wb + boff + (kk),             &Bs[buf][tid * 8]); \
    gl_lds16(Wb + boff + 64 * 1024 + (kk), &Bs[buf][2048 + tid * 8]); }

    STAGE(0, 0)
    __syncthreads();
    int cur = 0;
    for (int k0 = 0; k0 < 1024; k0 += 32) {
        if (k0 + 32 < 1024) STAGE(cur ^ 1, k0 + 32)
        short8 af[4], bfr[4];
#pragma unroll
        for (int mi = 0; mi < 4; ++mi)
            af[mi] = *(const short8*)&As[cur][(wr * 64 + mi * 16 + lr) * 32 + lg * 8];
#pragma unroll
        for (int ni = 0; ni < 4; ++ni)
            bfr[ni] = *(const short8*)&Bs[cur][(wc * 64 + ni * 16 + lr) * 32 + lg * 8];
#pragma unroll
        for (int mi = 0; mi < 4; ++mi)
#pragma unroll
            for (int ni = 0; ni < 4; ++ni)
                acc[mi][ni] = __builtin_amdgcn_mfma_f32_16x16x32_bf16(af[mi], bfr[ni], acc[mi][ni], 0, 0, 0);
        __syncthreads();
        cur ^= 1;
    }
#undef STAGE

#pragma unroll
    for (int mi = 0; mi < 4; ++mi) {
#pragma unroll
        for (int ni = 0; ni < 4; ++ni) {
            const int n = bn * 128 + wc * 64 + ni * 16 + lr;
#pragma unroll
            for (int i = 0; i < 4; ++i) {
                const int m = bm * 128 + wr * 64 + mi * 16 + lg * 4 + i;
                Cp[(size_t)m * 1024 + n] = acc[mi][ni][i] + bias[n];
            }
        }
    }
}

// ---------------- flash attention (round-15 version: reg-staged dbuf, padded LDS) ----------------
// grid (S/128, B*H), 256 threads. Wave w owns q rows qw..qw+31.
// DOUBLE-BUFFERED K/V LDS (36.9 KB), ONE barrier per tile:
//   { write prefetched tile t -> buf[t&1]; issue loads t+1; barrier; compute t }
// q (pre-scaled by log2e via Wq), k: [B,H,S,D] bf16. vtt: [B,H,S/64,D,64] bf16.
//   S^T = mfma(K,Q): C col = q = lane&31, row = kv = (reg&3)+8*(reg>>2)+4*(lane>>5)
// P = 2^(s-64) fixed-shift softmax; PV B-operand in-register via cvt_pk + permlane32.
__global__ __launch_bounds__(256, 4) void attn_kernel(const unsigned short* __restrict__ q,
                                                      const unsigned short* __restrict__ k,
                                                      const unsigned short* __restrict__ vtt,
                                                      unsigned short* __restrict__ o) {
    __shared__ unsigned short Kl[2][64][72];  // [buf][kv][d]
    __shared__ unsigned short Vl[2][64][72];  // [buf][d][kv]
    const int tid = threadIdx.x;
    const int lane = tid & 63, wid = tid >> 6;
    const int l31 = lane & 31, hi = lane >> 5;
    const int bh = blockIdx.y;
    const int qw = blockIdx.x * 128 + wid * 32;   // this wave's first q row
    const size_t base = (size_t)bh * NS * ND;     // same stride for q/k and vtt

    // Q fragments (B-operand): col = q = l31, k = d = 16m + 8*hi + j
    short8 qf[4];
    {
        const unsigned short* qp = q + base + (size_t)(qw + l31) * ND + 8 * hi;
#pragma unroll
        for (int m = 0; m < 4; ++m) qf[m] = *(const short8*)(qp + 16 * m);
    }

    float l_run = 0.f;                        // softmax denom (x 2^-64) for q-row l31
    f32x16 oa0, oa1, fz;
#pragma unroll
    for (int i = 0; i < 16; ++i) { oa0[i] = 0.f; oa1[i] = 0.f; fz[i] = 0.f; }

    // staging: 8KB tile / 256 threads = 32B per thread, contiguous
    const int strow = tid >> 2, stcol = (tid & 3) * 16;
    const unsigned short* ks = k   + base + tid * 16;   // + t*4096 per tile
    const unsigned short* vs = vtt + base + tid * 16;

    // prologue: prefetch tile 0 into regs (T14)
    short8 kr0 = *(const short8*)(ks);
    short8 kr1 = *(const short8*)(ks + 8);
    short8 vr0 = *(const short8*)(vs);
    short8 vr1 = *(const short8*)(vs + 8);

    for (int t = 0; t < NS / 64; ++t) {
        const int buf = t & 1;
        // write prefetched tile t (vmcnt wait for loads issued at t-1 lands here)
        *(short8*)&Kl[buf][strow][stcol]     = kr0;
        *(short8*)&Kl[buf][strow][stcol + 8] = kr1;
        *(short8*)&Vl[buf][strow][stcol]     = vr0;
        *(short8*)&Vl[buf][strow][stcol + 8] = vr1;

        // issue next tile's loads; they fly under this tile's compute
        if (t + 1 < NS / 64) {
            const unsigned short* ks2 = ks + (size_t)(t + 1) * 64 * ND;
            const unsigned short* vs2 = vs + (size_t)(t + 1) * 64 * ND;
            kr0 = *(const short8*)(ks2);
            kr1 = *(const short8*)(ks2 + 8);
            vr0 = *(const short8*)(vs2);
            vr1 = *(const short8*)(vs2 + 8);
        }

        __syncthreads();   // tile t visible to all waves

        // S^T = K·Q^T: two 32-kv subtiles, K=64 via 4 chained mfma each
        f32x16 st0, st1;
        __builtin_amdgcn_s_setprio(1);
        {
            short8 kf;
            kf = *(const short8*)&Kl[buf][l31][8 * hi];
            st0 = __builtin_amdgcn_mfma_f32_32x32x16_bf16(kf, qf[0], fz, 0, 0, 0);
            kf = *(const short8*)&Kl[buf][l31][16 + 8 * hi];
            st0 = __builtin_amdgcn_mfma_f32_32x32x16_bf16(kf, qf[1], st0, 0, 0, 0);
            kf = *(const short8*)&Kl[buf][l31][32 + 8 * hi];
            st0 = __builtin_amdgcn_mfma_f32_32x32x16_bf16(kf, qf[2], st0, 0, 0, 0);
            kf = *(const short8*)&Kl[buf][l31][48 + 8 * hi];
            st0 = __builtin_amdgcn_mfma_f32_32x32x16_bf16(kf, qf[3], st0, 0, 0, 0);
            kf = *(const short8*)&Kl[buf][32 + l31][8 * hi];
            st1 = __builtin_amdgcn_mfma_f32_32x32x16_bf16(kf, qf[0], fz, 0, 0, 0);
            kf = *(const short8*)&Kl[buf][32 + l31][16 + 8 * hi];
            st1 = __builtin_amdgcn_mfma_f32_32x32x16_bf16(kf, qf[1], st1, 0, 0, 0);
            kf = *(const short8*)&Kl[buf][32 + l31][32 + 8 * hi];
            st1 = __builtin_amdgcn_mfma_f32_32x32x16_bf16(kf, qf[2], st1, 0, 0, 0);
            kf = *(const short8*)&Kl[buf][32 + l31][48 + 8 * hi];
            st1 = __builtin_amdgcn_mfma_f32_32x32x16_bf16(kf, qf[3], st1, 0, 0, 0);
        }
        __builtin_amdgcn_s_setprio(0);

        // P = 2^(s - 64): packed subtract + native v_exp (1 op/elem; no max tracking)
        st0 = st0 - 64.0f;
        st1 = st1 - 64.0f;
#pragma unroll
        for (int i = 0; i < 16; ++i) st0[i] = exp2n(st0[i]);
#pragma unroll
        for (int i = 0; i < 16; ++i) st1[i] = exp2n(st1[i]);
        {   // packed tree sum of 32 exps -> denom
            f32x16 sv = st0 + st1;
            f32x8 s8 = __builtin_shufflevector(sv, sv, 0, 1, 2, 3, 4, 5, 6, 7)
                     + __builtin_shufflevector(sv, sv, 8, 9, 10, 11, 12, 13, 14, 15);
            f32x4 s4 = __builtin_shufflevector(s8, s8, 0, 1, 2, 3)
                     + __builtin_shufflevector(s8, s8, 4, 5, 6, 7);
            f32x2 s2 = __builtin_shufflevector(s4, s4, 0, 1)
                     + __builtin_shufflevector(s4, s4, 2, 3);
            float rs = s2[0] + s2[1];
            rs += __shfl_xor(rs, 32, 64);
            l_run += rs;
        }

        // P -> PV B-operand fragments, fully in-register (T12)
        short8 pf0, pf1, pf2, pf3;
#define MKPF(PF, SV, RB) { \
        unsigned int wa = packbf(SV[RB + 0], SV[RB + 1]); \
        unsigned int wb = packbf(SV[RB + 2], SV[RB + 3]); \
        unsigned int wc = packbf(SV[RB + 4], SV[RB + 5]); \
        unsigned int wd = packbf(SV[RB + 6], SV[RB + 7]); \
        asm("v_permlane32_swap_b32 %0, %1" : "+v"(wa), "+v"(wc)); \
        asm("v_permlane32_swap_b32 %0, %1" : "+v"(wb), "+v"(wd)); \
        u32x4 pw; pw[0] = wa; pw[1] = wb; pw[2] = wc; pw[3] = wd; \
        PF = __builtin_bit_cast(short8, pw); }
        MKPF(pf0, st0, 0)   // kv  0..15
        MKPF(pf1, st0, 8)   // kv 16..31
        MKPF(pf2, st1, 0)   // kv 32..47
        MKPF(pf3, st1, 8)   // kv 48..63
#undef MKPF

        // O^T += V^T · P^T  (A row = d, B col = q)
        __builtin_amdgcn_s_setprio(1);
        {
            short8 vf;
            vf = *(const short8*)&Vl[buf][l31][8 * hi];
            oa0 = __builtin_amdgcn_mfma_f32_32x32x16_bf16(vf, pf0, oa0, 0, 0, 0);
            vf = *(const short8*)&Vl[buf][l31][16 + 8 * hi];
            oa0 = __builtin_amdgcn_mfma_f32_32x32x16_bf16(vf, pf1, oa0, 0, 0, 0);
            vf = *(const short8*)&Vl[buf][l31][32 + 8 * hi];
            oa0 = __builtin_amdgcn_mfma_f32_32x32x16_bf16(vf, pf2, oa0, 0, 0, 0);
            vf = *(const short8*)&Vl[buf][l31][48 + 8 * hi];
            oa0 = __builtin_amdgcn_mfma_f32_32x32x16_bf16(vf, pf3, oa0, 0, 0, 0);
            vf = *(const short8*)&Vl[buf][32 + l31][8 * hi];
            oa1 = __builtin_amdgcn_mfma_f32_32x32x16_bf16(vf, pf0, oa1, 0, 0, 0);
            vf = *(const short8*)&Vl[buf][32 + l31][16 + 8 * hi];
            oa1 = __builtin_amdgcn_mfma_f32_32x32x16_bf16(vf, pf1, oa1, 0, 0, 0);
            vf = *(const short8*)&Vl[buf][32 + l31][32 + 8 * hi];
            oa1 = __builtin_amdgcn_mfma_f32_32x32x16_bf16(vf, pf2, oa1, 0, 0, 0);
            vf = *(const short8*)&Vl[buf][32 + l31][48 + 8 * hi];
            oa1 = __builtin_amdgcn_mfma_f32_32x32x16_bf16(vf, pf3, oa1, 0, 0, 0);
        }
        __builtin_amdgcn_s_setprio(0);
    }

    // epilogue: C reg r -> d = 32*t + 8*(r>>2) + 4*hi + (r&3); s = qw + l31
    const int b = bh >> 4, h = bh & 15;
    const float scl = 0.125f / l_run;   // softmax BEFORE scaling -> /8 here
    unsigned short* op = o + (((size_t)b * NS + (qw + l31)) * NH + h) * ND;
#pragma unroll
    for (int rq = 0; rq < 4; ++rq) {
        us4 p0, p1;
#pragma unroll
        for (int i = 0; i < 4; ++i) {
            p0[i] = f2bf(oa0[4 * rq + i] * scl);
            p1[i] = f2bf(oa1[4 * rq + i] * scl);
        }
        *(us4*)&op[8 * rq + 4 * hi]      = p0;
        *(us4*)&op[32 + 8 * rq + 4 * hi] = p1;
    }
}

extern "C" void kernel_launch(void* const* d_in, const int* in_sizes, int n_in,
                              void* d_out, int out_size, void* d_ws, size_t ws_size,
                              hipStream_t stream) {
    (void)in_sizes; (void)n_in; (void)out_size; (void)ws_size;
    const float* values  = (const float*)d_in[0];
    const float* keys    = (const float*)d_in[1];
    const float* queries = (const float*)d_in[2];
    const float* Wv = (const float*)d_in[3];
    const float* Wk = (const float*)d_in[4];
    const float* Wq = (const float*)d_in[5];
    const float* Wo = (const float*)d_in[6];
    const float* bo = (const float*)d_in[7];

    uint8_t* ws = (uint8_t*)d_ws;
    const size_t MB = (size_t)1 << 20;
    unsigned short* wvb = (unsigned short*)(ws + 0 * MB);
    unsigned short* wkb = (unsigned short*)(ws + 2 * MB);
    unsigned short* wqb = (unsigned short*)(ws + 4 * MB);
    unsigned short* wob = (unsigned short*)(ws + 6 * MB);
    unsigned short* qb  = (unsigned short*)(ws + 8 * MB);   // [B,H,S,D] bf16 (log2e-scaled)
    unsigned short* kb  = (unsigned short*)(ws + 24 * MB);  // [B,H,S,D] bf16
    unsigned short* vtb = (unsigned short*)(ws + 40 * MB);  // [B,H,S/64,D,64] bf16 (V^T kv-blocked)
    unsigned short* ab  = (unsigned short*)(ws + 56 * MB);  // [B,S,H,D] bf16 (attn out)

    cvt_w4_kernel<<<4096, 256, 0, stream>>>(Wv, Wk, Wq, Wo, wvb, wkb, wqb, wob);

    HybArgs hq;
    hq.a0 = queries; hq.a1 = keys; hq.a2 = values;
    hq.w0 = wqb;     hq.w1 = wkb; hq.w2 = wvb;
    hq.c0 = qb;      hq.c1 = kb;  hq.c2 = vtb;
    gemm_hyb<<<dim3(8, 64, 3), 256, 0, stream>>>(hq);

    attn_kernel<<<dim3(16, 64), 256, 0, stream>>>(qb, kb, vtb, ab);

    gemm_glds<<<dim3(8, 64), 256, 0, stream>>>(ab, wob, (float*)d_out, bo);
}

// Round 19
// 209.709 us; speedup vs baseline: 1.1703x; 1.1703x over previous
//
#include <hip/hip_runtime.h>
#include <stdint.h>

#define NB 4
#define NS 2048
#define NE 1024
#define NH 16
#define ND 64

typedef __attribute__((ext_vector_type(8))) short short8;
typedef __attribute__((ext_vector_type(2))) float f32x2;
typedef __attribute__((ext_vector_type(4))) float f32x4;
typedef __attribute__((ext_vector_type(8))) float f32x8;
typedef __attribute__((ext_vector_type(16))) float f32x16;
typedef __attribute__((ext_vector_type(4))) unsigned short us4;
typedef __attribute__((ext_vector_type(4))) unsigned int u32x4;
typedef __attribute__((ext_vector_type(2))) __bf16 bf16x2;

#define LOG2E 1.4426950408889634f

// f32 -> bf16 RNE via native cast (clang emits v_cvt_pk_bf16_f32 pairs).
__device__ __forceinline__ unsigned short f2bf(float f) {
    return __builtin_bit_cast(unsigned short, static_cast<__bf16>(f));
}
__device__ __forceinline__ unsigned int packbf(float lo, float hi_) {
    f32x2 v; v[0] = lo; v[1] = hi_;
    return __builtin_bit_cast(unsigned int, __builtin_convertvector(v, bf16x2));
}
// native v_exp_f32 (2^x) - avoids OCML exp2f's denormal-fixup sequence
__device__ __forceinline__ float exp2n(float x) {
    float y;
    asm("v_exp_f32 %0, %1" : "=v"(y) : "v"(x));
    return y;
}
// async global->LDS, 16B per lane (LDS dest = wave-uniform base + lane*16)
__device__ __forceinline__ void gl_lds16(const void* g, void* l) {
    __builtin_amdgcn_global_load_lds(
        (const __attribute__((address_space(1))) unsigned int*)g,
        (__attribute__((address_space(3))) unsigned int*)l, 16, 0, 0);
}

// ---------------- weight fp32 -> bf16 (weights only), one launch ----------------
// Wq (g==2) pre-scaled by log2e so attention logits arrive in exp2 domain.
__global__ __launch_bounds__(256) void cvt_w4_kernel(const float* __restrict__ w0,
                                                     const float* __restrict__ w1,
                                                     const float* __restrict__ w2,
                                                     const float* __restrict__ w3,
                                                     unsigned short* __restrict__ d0,
                                                     unsigned short* __restrict__ d1,
                                                     unsigned short* __restrict__ d2,
                                                     unsigned short* __restrict__ d3) {
    const int g = blockIdx.x >> 10;            // which weight (1024 blocks each)
    const float* src = g == 0 ? w0 : g == 1 ? w1 : g == 2 ? w2 : w3;
    unsigned short* dst = g == 0 ? d0 : g == 1 ? d1 : g == 2 ? d2 : d3;
    const float scl = (g == 2) ? LOG2E : 1.0f;
    const int i = ((blockIdx.x & 1023) * 256 + threadIdx.x) * 4;
    f32x4 f = *(const f32x4*)(src + i);
    us4 o;
#pragma unroll
    for (int j = 0; j < 4; ++j) o[j] = f2bf(f[j] * scl);
    *(us4*)(dst + i) = o;
}

// ---------------- hybrid QKV GEMM: C = A_f32 @ W_bf16^T ----------------
// A fp32 [M,1024] converted to bf16 in-register during staging (pad-36 LDS: stride
// 72B = 18 banks, gcd(18,32)=2 -> ~4-way writes / ~2-way reads); W bf16 via
// global_load_lds (linear dbuf). Per iter: LOAD_A(t+1) first (oldest outstanding,
// so WRITE_A waits only on A), then W gloads(t+1); compute(t); WRITE_A; barrier.
// Grid is bm-FASTEST (64,8,3): 64 consecutive blocks share one 256KB W-tile (W
// stays L2-hot on every XCD); A streams once. (bn-fastest quadrupled FETCH via
// XCD round-robin - round-18 lesson.)
// z=0,1 -> bf16 [B,H,S,D]; z==2 -> V^T kv-blocked [B,H,S/64,D,64].
struct HybArgs {
    const float *a0, *a1, *a2;
    const unsigned short *w0, *w1, *w2;
    void *c0, *c1, *c2;
};

__global__ __launch_bounds__(256) void gemm_hyb(HybArgs args) {
    __shared__ unsigned short As[2][128][36];             // pad 36: 2-way-ish pattern
    __shared__ __align__(16) unsigned short Bs[2][4096];  // linear, gload_lds dest
    const int tid = threadIdx.x;
    const int bm = blockIdx.x, bn = blockIdx.y, z = blockIdx.z;   // bm fastest
    const float* Ab          = z == 0 ? args.a0 : z == 1 ? args.a1 : args.a2;
    const unsigned short* Wb = z == 0 ? args.w0 : z == 1 ? args.w1 : args.w2;
    void* Cp                 = z == 0 ? args.c0 : z == 1 ? args.c1 : args.c2;
    const int lane = tid & 63, wid = tid >> 6;
    const int lr = lane & 15, lg = lane >> 4;
    const int wr = wid >> 1, wc = wid & 1;
    const int srow = tid >> 1, shalf = tid & 1;

    const float* apF = Ab + (size_t)(bm * 128 + srow) * 1024 + shalf * 16;
    const size_t boff = (size_t)(bn * 128 + (tid >> 2)) * 1024 + (tid & 3) * 8;

    f32x4 acc[4][4];
#pragma unroll
    for (int a = 0; a < 4; ++a)
#pragma unroll
        for (int b = 0; b < 4; ++b) acc[a][b] = (f32x4){0.f, 0.f, 0.f, 0.f};

#define STAGE_W(buf, kk) { \
    gl_lds16(Wb + boff + (kk),             &Bs[buf][tid * 8]); \
    gl_lds16(Wb + boff + 64 * 1024 + (kk), &Bs[buf][2048 + tid * 8]); }
#define LOAD_A(kk) { \
    pa0 = *(const f32x4*)(apF + (kk)); \
    pa1 = *(const f32x4*)(apF + (kk) + 4); \
    pa2 = *(const f32x4*)(apF + (kk) + 8); \
    pa3 = *(const f32x4*)(apF + (kk) + 12); }
#define WRITE_A(buf) { \
    short8 p0, p1; \
    for (int j = 0; j < 4; ++j) { \
        p0[j] = (short)f2bf(pa0[j]); p0[j + 4] = (short)f2bf(pa1[j]); \
        p1[j] = (short)f2bf(pa2[j]); p1[j + 4] = (short)f2bf(pa3[j]); } \
    *(short8*)&As[buf][srow][shalf * 16]     = p0; \
    *(short8*)&As[buf][srow][shalf * 16 + 8] = p1; }

    f32x4 pa0, pa1, pa2, pa3;
    LOAD_A(0)
    STAGE_W(0, 0)
    WRITE_A(0)
    __syncthreads();   // W tile 0 drained (vmcnt 0), A writes visible
    int cur = 0;
    for (int k0 = 0; k0 < 1024; k0 += 32) {
        const int last = (k0 + 32 >= 1024);
        if (!last) {
            LOAD_A(k0 + 32)             // issue A first: oldest outstanding VMEM
            STAGE_W(cur ^ 1, k0 + 32)   // W gloads fly under compute + WRITE_A
        }
        short8 af[4], bfr[4];
#pragma unroll
        for (int mi = 0; mi < 4; ++mi)
            af[mi] = *(const short8*)&As[cur][wr * 64 + mi * 16 + lr][lg * 8];
#pragma unroll
        for (int ni = 0; ni < 4; ++ni)
            bfr[ni] = *(const short8*)&Bs[cur][(wc * 64 + ni * 16 + lr) * 32 + lg * 8];
#pragma unroll
        for (int mi = 0; mi < 4; ++mi)
#pragma unroll
            for (int ni = 0; ni < 4; ++ni)
                acc[mi][ni] = __builtin_amdgcn_mfma_f32_16x16x32_bf16(af[mi], bfr[ni], acc[mi][ni], 0, 0, 0);
        if (!last) WRITE_A(cur ^ 1)     // waits only A loads, overlaps W
        __syncthreads();                // drains W loads + A writes visible
        cur ^= 1;
    }
#undef STAGE_W
#undef LOAD_A
#undef WRITE_A

#pragma unroll
    for (int mi = 0; mi < 4; ++mi) {
#pragma unroll
        for (int ni = 0; ni < 4; ++ni) {
            const int n = bn * 128 + wc * 64 + ni * 16 + lr;
            if (z == 2) {
                // V^T kv-blocked: [B,H,S/64,D,64]; i -> s consecutive within a 64-block.
                const int m0 = bm * 128 + wr * 64 + mi * 16 + lg * 4;
                const int b = m0 >> 11, s0 = m0 & 2047;
                const int h = n >> 6, d = n & 63;
                us4 pk;
#pragma unroll
                for (int i = 0; i < 4; ++i) pk[i] = f2bf(acc[mi][ni][i]);
                const size_t idx = ((((size_t)b * NH + h) * (NS / 64) + (s0 >> 6)) * ND + d) * 64 + (s0 & 63);
                *(us4*)&((unsigned short*)Cp)[idx] = pk;
            } else {
#pragma unroll
                for (int i = 0; i < 4; ++i) {
                    const int m = bm * 128 + wr * 64 + mi * 16 + lg * 4 + i;
                    const int b = m >> 11, s = m & 2047, h = n >> 6, d = n & 63;
                    ((unsigned short*)Cp)[(((size_t)b * NH + h) * NS + s) * ND + d] = f2bf(acc[mi][ni][i]);
                }
            }
        }
    }
}

// ---------------- epilogue GEMM via global_load_lds: fp32 C = A_bf16 @ W^T + bias ----------------
__global__ __launch_bounds__(256) void gemm_glds(const unsigned short* __restrict__ Ab,
                                                 const unsigned short* __restrict__ Wb,
                                                 float* __restrict__ Cp,
                                                 const float* __restrict__ bias) {
    __shared__ __align__(16) unsigned short As[2][4096];
    __shared__ __align__(16) unsigned short Bs[2][4096];
    const int tid = threadIdx.x;
    const int bm = blockIdx.x, bn = blockIdx.y;   // bm fastest (W-tile L2 reuse)
    const int lane = tid & 63, wid = tid >> 6;
    const int lr = lane & 15, lg = lane >> 4;
    const int wr = wid >> 1, wc = wid & 1;

    const size_t aoff = (size_t)(bm * 128 + (tid >> 2)) * 1024 + (tid & 3) * 8;
    const size_t boff = (size_t)(bn * 128 + (tid >> 2)) * 1024 + (tid & 3) * 8;

    f32x4 acc[4][4];
#pragma unroll
    for (int a = 0; a < 4; ++a)
#pragma unroll
        for (int b = 0; b < 4; ++b) acc[a][b] = (f32x4){0.f, 0.f, 0.f, 0.f};

#define STAGE(buf, kk) { \
    gl_lds16(Ab + aoff + (kk),             &As[buf][tid * 8]); \
    gl_lds16(Ab + aoff + 64 * 1024 + (kk), &As[buf][2048 + tid * 8]); \
    gl_lds16(Wb + boff + (kk),             &Bs[buf][tid * 8]); \
    gl_lds16(Wb + boff + 64 * 1024 + (kk), &Bs[buf][2048 + tid * 8]); }

    STAGE(0, 0)
    __syncthreads();
    int cur = 0;
    for (int k0 = 0; k0 < 1024; k0 += 32) {
        if (k0 + 32 < 1024) STAGE(cur ^ 1, k0 + 32)
        short8 af[4], bfr[4];
#pragma unroll
        for (int mi = 0; mi < 4; ++mi)
            af[mi] = *(const short8*)&As[cur][(wr * 64 + mi * 16 + lr) * 32 + lg * 8];
#pragma unroll
        for (int ni = 0; ni < 4; ++ni)
            bfr[ni] = *(const short8*)&Bs[cur][(wc * 64 + ni * 16 + lr) * 32 + lg * 8];
#pragma unroll
        for (int mi = 0; mi < 4; ++mi)
#pragma unroll
            for (int ni = 0; ni < 4; ++ni)
                acc[mi][ni] = __builtin_amdgcn_mfma_f32_16x16x32_bf16(af[mi], bfr[ni], acc[mi][ni], 0, 0, 0);
        __syncthreads();
        cur ^= 1;
    }
#undef STAGE

#pragma unroll
    for (int mi = 0; mi < 4; ++mi) {
#pragma unroll
        for (int ni = 0; ni < 4; ++ni) {
            const int n = bn * 128 + wc * 64 + ni * 16 + lr;
#pragma unroll
            for (int i = 0; i < 4; ++i) {
                const int m = bm * 128 + wr * 64 + mi * 16 + lg * 4 + i;
                Cp[(size_t)m * 1024 + n] = acc[mi][ni][i] + bias[n];
            }
        }
    }
}

// ---------------- flash attention (round-15 version: reg-staged dbuf, padded LDS) ----------------
// grid (S/128, B*H), 256 threads. Wave w owns q rows qw..qw+31.
// DOUBLE-BUFFERED K/V LDS (36.9 KB), ONE barrier per tile:
//   { write prefetched tile t -> buf[t&1]; issue loads t+1; barrier; compute t }
// q (pre-scaled by log2e via Wq), k: [B,H,S,D] bf16. vtt: [B,H,S/64,D,64] bf16.
//   S^T = mfma(K,Q): C col = q = lane&31, row = kv = (reg&3)+8*(reg>>2)+4*(lane>>5)
// P = 2^(s-64) fixed-shift softmax; PV B-operand in-register via cvt_pk + permlane32.
__global__ __launch_bounds__(256, 4) void attn_kernel(const unsigned short* __restrict__ q,
                                                      const unsigned short* __restrict__ k,
                                                      const unsigned short* __restrict__ vtt,
                                                      unsigned short* __restrict__ o) {
    __shared__ unsigned short Kl[2][64][72];  // [buf][kv][d]
    __shared__ unsigned short Vl[2][64][72];  // [buf][d][kv]
    const int tid = threadIdx.x;
    const int lane = tid & 63, wid = tid >> 6;
    const int l31 = lane & 31, hi = lane >> 5;
    const int bh = blockIdx.y;
    const int qw = blockIdx.x * 128 + wid * 32;   // this wave's first q row
    const size_t base = (size_t)bh * NS * ND;     // same stride for q/k and vtt

    // Q fragments (B-operand): col = q = l31, k = d = 16m + 8*hi + j
    short8 qf[4];
    {
        const unsigned short* qp = q + base + (size_t)(qw + l31) * ND + 8 * hi;
#pragma unroll
        for (int m = 0; m < 4; ++m) qf[m] = *(const short8*)(qp + 16 * m);
    }

    float l_run = 0.f;                        // softmax denom (x 2^-64) for q-row l31
    f32x16 oa0, oa1, fz;
#pragma unroll
    for (int i = 0; i < 16; ++i) { oa0[i] = 0.f; oa1[i] = 0.f; fz[i] = 0.f; }

    // staging: 8KB tile / 256 threads = 32B per thread, contiguous
    const int strow = tid >> 2, stcol = (tid & 3) * 16;
    const unsigned short* ks = k   + base + tid * 16;   // + t*4096 per tile
    const unsigned short* vs = vtt + base + tid * 16;

    // prologue: prefetch tile 0 into regs (T14)
    short8 kr0 = *(const short8*)(ks);
    short8 kr1 = *(const short8*)(ks + 8);
    short8 vr0 = *(const short8*)(vs);
    short8 vr1 = *(const short8*)(vs + 8);

    for (int t = 0; t < NS / 64; ++t) {
        const int buf = t & 1;
        // write prefetched tile t (vmcnt wait for loads issued at t-1 lands here)
        *(short8*)&Kl[buf][strow][stcol]     = kr0;
        *(short8*)&Kl[buf][strow][stcol + 8] = kr1;
        *(short8*)&Vl[buf][strow][stcol]     = vr0;
        *(short8*)&Vl[buf][strow][stcol + 8] = vr1;

        // issue next tile's loads; they fly under this tile's compute
        if (t + 1 < NS / 64) {
            const unsigned short* ks2 = ks + (size_t)(t + 1) * 64 * ND;
            const unsigned short* vs2 = vs + (size_t)(t + 1) * 64 * ND;
            kr0 = *(const short8*)(ks2);
            kr1 = *(const short8*)(ks2 + 8);
            vr0 = *(const short8*)(vs2);
            vr1 = *(const short8*)(vs2 + 8);
        }

        __syncthreads();   // tile t visible to all waves

        // S^T = K·Q^T: two 32-kv subtiles, K=64 via 4 chained mfma each
        f32x16 st0, st1;
        __builtin_amdgcn_s_setprio(1);
        {
            short8 kf;
            kf = *(const short8*)&Kl[buf][l31][8 * hi];
            st0 = __builtin_amdgcn_mfma_f32_32x32x16_bf16(kf, qf[0], fz, 0, 0, 0);
            kf = *(const short8*)&Kl[buf][l31][16 + 8 * hi];
            st0 = __builtin_amdgcn_mfma_f32_32x32x16_bf16(kf, qf[1], st0, 0, 0, 0);
            kf = *(const short8*)&Kl[buf][l31][32 + 8 * hi];
            st0 = __builtin_amdgcn_mfma_f32_32x32x16_bf16(kf, qf[2], st0, 0, 0, 0);
            kf = *(const short8*)&Kl[buf][l31][48 + 8 * hi];
            st0 = __builtin_amdgcn_mfma_f32_32x32x16_bf16(kf, qf[3], st0, 0, 0, 0);
            kf = *(const short8*)&Kl[buf][32 + l31][8 * hi];
            st1 = __builtin_amdgcn_mfma_f32_32x32x16_bf16(kf, qf[0], fz, 0, 0, 0);
            kf = *(const short8*)&Kl[buf][32 + l31][16 + 8 * hi];
            st1 = __builtin_amdgcn_mfma_f32_32x32x16_bf16(kf, qf[1], st1, 0, 0, 0);
            kf = *(const short8*)&Kl[buf][32 + l31][32 + 8 * hi];
            st1 = __builtin_amdgcn_mfma_f32_32x32x16_bf16(kf, qf[2], st1, 0, 0, 0);
            kf = *(const short8*)&Kl[buf][32 + l31][48 + 8 * hi];
            st1 = __builtin_amdgcn_mfma_f32_32x32x16_bf16(kf, qf[3], st1, 0, 0, 0);
        }
        __builtin_amdgcn_s_setprio(0);

        // P = 2^(s - 64): packed subtract + native v_exp (1 op/elem; no max tracking)
        st0 = st0 - 64.0f;
        st1 = st1 - 64.0f;
#pragma unroll
        for (int i = 0; i < 16; ++i) st0[i] = exp2n(st0[i]);
#pragma unroll
        for (int i = 0; i < 16; ++i) st1[i] = exp2n(st1[i]);
        {   // packed tree sum of 32 exps -> denom
            f32x16 sv = st0 + st1;
            f32x8 s8 = __builtin_shufflevector(sv, sv, 0, 1, 2, 3, 4, 5, 6, 7)
                     + __builtin_shufflevector(sv, sv, 8, 9, 10, 11, 12, 13, 14, 15);
            f32x4 s4 = __builtin_shufflevector(s8, s8, 0, 1, 2, 3)
                     + __builtin_shufflevector(s8, s8, 4, 5, 6, 7);
            f32x2 s2 = __builtin_shufflevector(s4, s4, 0, 1)
                     + __builtin_shufflevector(s4, s4, 2, 3);
            float rs = s2[0] + s2[1];
            rs += __shfl_xor(rs, 32, 64);
            l_run += rs;
        }

        // P -> PV B-operand fragments, fully in-register (T12)
        short8 pf0, pf1, pf2, pf3;
#define MKPF(PF, SV, RB) { \
        unsigned int wa = packbf(SV[RB + 0], SV[RB + 1]); \
        unsigned int wb = packbf(SV[RB + 2], SV[RB + 3]); \
        unsigned int wc = packbf(SV[RB + 4], SV[RB + 5]); \
        unsigned int wd = packbf(SV[RB + 6], SV[RB + 7]); \
        asm("v_permlane32_swap_b32 %0, %1" : "+v"(wa), "+v"(wc)); \
        asm("v_permlane32_swap_b32 %0, %1" : "+v"(wb), "+v"(wd)); \
        u32x4 pw; pw[0] = wa; pw[1] = wb; pw[2] = wc; pw[3] = wd; \
        PF = __builtin_bit_cast(short8, pw); }
        MKPF(pf0, st0, 0)   // kv  0..15
        MKPF(pf1, st0, 8)   // kv 16..31
        MKPF(pf2, st1, 0)   // kv 32..47
        MKPF(pf3, st1, 8)   // kv 48..63
#undef MKPF

        // O^T += V^T · P^T  (A row = d, B col = q)
        __builtin_amdgcn_s_setprio(1);
        {
            short8 vf;
            vf = *(const short8*)&Vl[buf][l31][8 * hi];
            oa0 = __builtin_amdgcn_mfma_f32_32x32x16_bf16(vf, pf0, oa0, 0, 0, 0);
            vf = *(const short8*)&Vl[buf][l31][16 + 8 * hi];
            oa0 = __builtin_amdgcn_mfma_f32_32x32x16_bf16(vf, pf1, oa0, 0, 0, 0);
            vf = *(const short8*)&Vl[buf][l31][32 + 8 * hi];
            oa0 = __builtin_amdgcn_mfma_f32_32x32x16_bf16(vf, pf2, oa0, 0, 0, 0);
            vf = *(const short8*)&Vl[buf][l31][48 + 8 * hi];
            oa0 = __builtin_amdgcn_mfma_f32_32x32x16_bf16(vf, pf3, oa0, 0, 0, 0);
            vf = *(const short8*)&Vl[buf][32 + l31][8 * hi];
            oa1 = __builtin_amdgcn_mfma_f32_32x32x16_bf16(vf, pf0, oa1, 0, 0, 0);
            vf = *(const short8*)&Vl[buf][32 + l31][16 + 8 * hi];
            oa1 = __builtin_amdgcn_mfma_f32_32x32x16_bf16(vf, pf1, oa1, 0, 0, 0);
            vf = *(const short8*)&Vl[buf][32 + l31][32 + 8 * hi];
            oa1 = __builtin_amdgcn_mfma_f32_32x32x16_bf16(vf, pf2, oa1, 0, 0, 0);
            vf = *(const short8*)&Vl[buf][32 + l31][48 + 8 * hi];
            oa1 = __builtin_amdgcn_mfma_f32_32x32x16_bf16(vf, pf3, oa1, 0, 0, 0);
        }
        __builtin_amdgcn_s_setprio(0);
    }

    // epilogue: C reg r -> d = 32*t + 8*(r>>2) + 4*hi + (r&3); s = qw + l31
    const int b = bh >> 4, h = bh & 15;
    const float scl = 0.125f / l_run;   // softmax BEFORE scaling -> /8 here
    unsigned short* op = o + (((size_t)b * NS + (qw + l31)) * NH + h) * ND;
#pragma unroll
    for (int rq = 0; rq < 4; ++rq) {
        us4 p0, p1;
#pragma unroll
        for (int i = 0; i < 4; ++i) {
            p0[i] = f2bf(oa0[4 * rq + i] * scl);
            p1[i] = f2bf(oa1[4 * rq + i] * scl);
        }
        *(us4*)&op[8 * rq + 4 * hi]      = p0;
        *(us4*)&op[32 + 8 * rq + 4 * hi] = p1;
    }
}

extern "C" void kernel_launch(void* const* d_in, const int* in_sizes, int n_in,
                              void* d_out, int out_size, void* d_ws, size_t ws_size,
                              hipStream_t stream) {
    (void)in_sizes; (void)n_in; (void)out_size; (void)ws_size;
    const float* values  = (const float*)d_in[0];
    const float* keys    = (const float*)d_in[1];
    const float* queries = (const float*)d_in[2];
    const float* Wv = (const float*)d_in[3];
    const float* Wk = (const float*)d_in[4];
    const float* Wq = (const float*)d_in[5];
    const float* Wo = (const float*)d_in[6];
    const float* bo = (const float*)d_in[7];

    uint8_t* ws = (uint8_t*)d_ws;
    const size_t MB = (size_t)1 << 20;
    unsigned short* wvb = (unsigned short*)(ws + 0 * MB);
    unsigned short* wkb = (unsigned short*)(ws + 2 * MB);
    unsigned short* wqb = (unsigned short*)(ws + 4 * MB);
    unsigned short* wob = (unsigned short*)(ws + 6 * MB);
    unsigned short* qb  = (unsigned short*)(ws + 8 * MB);   // [B,H,S,D] bf16 (log2e-scaled)
    unsigned short* kb  = (unsigned short*)(ws + 24 * MB);  // [B,H,S,D] bf16
    unsigned short* vtb = (unsigned short*)(ws + 40 * MB);  // [B,H,S/64,D,64] bf16 (V^T kv-blocked)
    unsigned short* ab  = (unsigned short*)(ws + 56 * MB);  // [B,S,H,D] bf16 (attn out)

    cvt_w4_kernel<<<4096, 256, 0, stream>>>(Wv, Wk, Wq, Wo, wvb, wkb, wqb, wob);

    HybArgs hq;
    hq.a0 = queries; hq.a1 = keys; hq.a2 = values;
    hq.w0 = wqb;     hq.w1 = wkb; hq.w2 = wvb;
    hq.c0 = qb;      hq.c1 = kb;  hq.c2 = vtb;
    gemm_hyb<<<dim3(64, 8, 3), 256, 0, stream>>>(hq);

    attn_kernel<<<dim3(16, 64), 256, 0, stream>>>(qb, kb, vtb, ab);

    gemm_glds<<<dim3(64, 8), 256, 0, stream>>>(ab, wob, (float*)d_out, bo);
}

// Round 21
// 205.836 us; speedup vs baseline: 1.1923x; 1.0188x over previous
//
#include <hip/hip_runtime.h>
#include <stdint.h>

#define NB 4
#define NS 2048
#define NE 1024
#define NH 16
#define ND 64

typedef __attribute__((ext_vector_type(8))) short short8;
typedef __attribute__((ext_vector_type(2))) float f32x2;
typedef __attribute__((ext_vector_type(4))) float f32x4;
typedef __attribute__((ext_vector_type(8))) float f32x8;
typedef __attribute__((ext_vector_type(16))) float f32x16;
typedef __attribute__((ext_vector_type(4))) unsigned short us4;
typedef __attribute__((ext_vector_type(4))) unsigned int u32x4;
typedef __attribute__((ext_vector_type(2))) __bf16 bf16x2;

#define LOG2E 1.4426950408889634f

// f32 -> bf16 RNE via native cast (clang emits v_cvt_pk_bf16_f32 pairs).
__device__ __forceinline__ unsigned short f2bf(float f) {
    return __builtin_bit_cast(unsigned short, static_cast<__bf16>(f));
}
__device__ __forceinline__ unsigned int packbf(float lo, float hi_) {
    f32x2 v; v[0] = lo; v[1] = hi_;
    return __builtin_bit_cast(unsigned int, __builtin_convertvector(v, bf16x2));
}
// native v_exp_f32 (2^x) - avoids OCML exp2f's denormal-fixup sequence
__device__ __forceinline__ float exp2n(float x) {
    float y;
    asm("v_exp_f32 %0, %1" : "=v"(y) : "v"(x));
    return y;
}
// async global->LDS, 16B per lane (LDS dest = wave-uniform base + lane*16)
__device__ __forceinline__ void gl_lds16(const void* g, void* l) {
    __builtin_amdgcn_global_load_lds(
        (const __attribute__((address_space(1))) unsigned int*)g,
        (__attribute__((address_space(3))) unsigned int*)l, 16, 0, 0);
}

// ---------------- weight fp32 -> bf16 (weights only), one launch ----------------
// Wq (g==2) pre-scaled by log2e so attention logits arrive in exp2 domain.
__global__ __launch_bounds__(256) void cvt_w4_kernel(const float* __restrict__ w0,
                                                     const float* __restrict__ w1,
                                                     const float* __restrict__ w2,
                                                     const float* __restrict__ w3,
                                                     unsigned short* __restrict__ d0,
                                                     unsigned short* __restrict__ d1,
                                                     unsigned short* __restrict__ d2,
                                                     unsigned short* __restrict__ d3) {
    const int g = blockIdx.x >> 10;            // which weight (1024 blocks each)
    const float* src = g == 0 ? w0 : g == 1 ? w1 : g == 2 ? w2 : w3;
    unsigned short* dst = g == 0 ? d0 : g == 1 ? d1 : g == 2 ? d2 : d3;
    const float scl = (g == 2) ? LOG2E : 1.0f;
    const int i = ((blockIdx.x & 1023) * 256 + threadIdx.x) * 4;
    f32x4 f = *(const f32x4*)(src + i);
    us4 o;
#pragma unroll
    for (int j = 0; j < 4; ++j) o[j] = f2bf(f[j] * scl);
    *(us4*)(dst + i) = o;
}

// ---------------- hybrid QKV GEMM: C = A_f32 @ W_bf16^T ----------------
// A fp32 [M,1024] converted to bf16 in-register during staging (pad-40 LDS);
// W bf16 via global_load_lds (linear dbuf). One barrier per BK=32 iter.
// Grid bm-FASTEST: 64 consecutive blocks share one W panel (L2-hot per XCD),
// A streams once (bn-fastest quadrupled FETCH via XCD round-robin, r18 lesson).
// z=0,1 -> bf16 [B,H,S,D]; z==2 -> V^T kv-blocked [B,H,S/64,D,64].
struct HybArgs {
    const float *a0, *a1, *a2;
    const unsigned short *w0, *w1, *w2;
    void *c0, *c1, *c2;
};

__global__ __launch_bounds__(256) void gemm_hyb(HybArgs args) {
    __shared__ unsigned short As[2][128][40];             // pad 40: proven r17 layout
    __shared__ __align__(16) unsigned short Bs[2][4096];  // linear, gload_lds dest
    const int tid = threadIdx.x;
    const int bm = blockIdx.x, bn = blockIdx.y, z = blockIdx.z;   // bm fastest
    const float* Ab          = z == 0 ? args.a0 : z == 1 ? args.a1 : args.a2;
    const unsigned short* Wb = z == 0 ? args.w0 : z == 1 ? args.w1 : args.w2;
    void* Cp                 = z == 0 ? args.c0 : z == 1 ? args.c1 : args.c2;
    const int lane = tid & 63, wid = tid >> 6;
    const int lr = lane & 15, lg = lane >> 4;
    const int wr = wid >> 1, wc = wid & 1;
    const int srow = tid >> 1, shalf = tid & 1;

    const float* apF = Ab + (size_t)(bm * 128 + srow) * 1024 + shalf * 16;
    const size_t boff = (size_t)(bn * 128 + (tid >> 2)) * 1024 + (tid & 3) * 8;

    f32x4 acc[4][4];
#pragma unroll
    for (int a = 0; a < 4; ++a)
#pragma unroll
        for (int b = 0; b < 4; ++b) acc[a][b] = (f32x4){0.f, 0.f, 0.f, 0.f};

#define STAGE_W(buf, kk) { \
    gl_lds16(Wb + boff + (kk),             &Bs[buf][tid * 8]); \
    gl_lds16(Wb + boff + 64 * 1024 + (kk), &Bs[buf][2048 + tid * 8]); }
#define LOAD_A(kk) { \
    pa0 = *(const f32x4*)(apF + (kk)); \
    pa1 = *(const f32x4*)(apF + (kk) + 4); \
    pa2 = *(const f32x4*)(apF + (kk) + 8); \
    pa3 = *(const f32x4*)(apF + (kk) + 12); }
#define WRITE_A(buf) { \
    short8 p0, p1; \
    for (int j = 0; j < 4; ++j) { \
        p0[j] = (short)f2bf(pa0[j]); p0[j + 4] = (short)f2bf(pa1[j]); \
        p1[j] = (short)f2bf(pa2[j]); p1[j + 4] = (short)f2bf(pa3[j]); } \
    *(short8*)&As[buf][srow][shalf * 16]     = p0; \
    *(short8*)&As[buf][srow][shalf * 16 + 8] = p1; }

    f32x4 pa0, pa1, pa2, pa3;
    LOAD_A(0)
    STAGE_W(0, 0)
    WRITE_A(0)
    __syncthreads();   // W tile 0 drained (vmcnt 0), A writes visible
    int cur = 0;
    for (int k0 = 0; k0 < 1024; k0 += 32) {
        const int last = (k0 + 32 >= 1024);
        if (!last) {
            STAGE_W(cur ^ 1, k0 + 32)   // flies under this tile's compute
            LOAD_A(k0 + 32)
        }
        short8 af[4], bfr[4];
#pragma unroll
        for (int mi = 0; mi < 4; ++mi)
            af[mi] = *(const short8*)&As[cur][wr * 64 + mi * 16 + lr][lg * 8];
#pragma unroll
        for (int ni = 0; ni < 4; ++ni)
            bfr[ni] = *(const short8*)&Bs[cur][(wc * 64 + ni * 16 + lr) * 32 + lg * 8];
#pragma unroll
        for (int mi = 0; mi < 4; ++mi)
#pragma unroll
            for (int ni = 0; ni < 4; ++ni)
                acc[mi][ni] = __builtin_amdgcn_mfma_f32_16x16x32_bf16(af[mi], bfr[ni], acc[mi][ni], 0, 0, 0);
        if (!last) WRITE_A(cur ^ 1)     // A loads completed during compute
        __syncthreads();                // drains W loads + A writes visible
        cur ^= 1;
    }
#undef STAGE_W
#undef LOAD_A
#undef WRITE_A

#pragma unroll
    for (int mi = 0; mi < 4; ++mi) {
#pragma unroll
        for (int ni = 0; ni < 4; ++ni) {
            const int n = bn * 128 + wc * 64 + ni * 16 + lr;
            if (z == 2) {
                // V^T kv-blocked: [B,H,S/64,D,64]; i -> s consecutive within a 64-block.
                const int m0 = bm * 128 + wr * 64 + mi * 16 + lg * 4;
                const int b = m0 >> 11, s0 = m0 & 2047;
                const int h = n >> 6, d = n & 63;
                us4 pk;
#pragma unroll
                for (int i = 0; i < 4; ++i) pk[i] = f2bf(acc[mi][ni][i]);
                const size_t idx = ((((size_t)b * NH + h) * (NS / 64) + (s0 >> 6)) * ND + d) * 64 + (s0 & 63);
                *(us4*)&((unsigned short*)Cp)[idx] = pk;
            } else {
#pragma unroll
                for (int i = 0; i < 4; ++i) {
                    const int m = bm * 128 + wr * 64 + mi * 16 + lg * 4 + i;
                    const int b = m >> 11, s = m & 2047, h = n >> 6, d = n & 63;
                    ((unsigned short*)Cp)[(((size_t)b * NH + h) * NS + s) * ND + d] = f2bf(acc[mi][ni][i]);
                }
            }
        }
    }
}

// ---------------- epilogue GEMM via global_load_lds: fp32 C = A_bf16 @ W^T + bias ----------------
__global__ __launch_bounds__(256) void gemm_glds(const unsigned short* __restrict__ Ab,
                                                 const unsigned short* __restrict__ Wb,
                                                 float* __restrict__ Cp,
                                                 const float* __restrict__ bias) {
    __shared__ __align__(16) unsigned short As[2][4096];
    __shared__ __align__(16) unsigned short Bs[2][4096];
    const int tid = threadIdx.x;
    const int bm = blockIdx.x, bn = blockIdx.y;   // bm fastest (W-panel L2 reuse)
    const int lane = tid & 63, wid = tid >> 6;
    const int lr = lane & 15, lg = lane >> 4;
    const int wr = wid >> 1, wc = wid & 1;

    const size_t aoff = (size_t)(bm * 128 + (tid >> 2)) * 1024 + (tid & 3) * 8;
    const size_t boff = (size_t)(bn * 128 + (tid >> 2)) * 1024 + (tid & 3) * 8;

    f32x4 acc[4][4];
#pragma unroll
    for (int a = 0; a < 4; ++a)
#pragma unroll
        for (int b = 0; b < 4; ++b) acc[a][b] = (f32x4){0.f, 0.f, 0.f, 0.f};

#define STAGE(buf, kk) { \
    gl_lds16(Ab + aoff + (kk),             &As[buf][tid * 8]); \
    gl_lds16(Ab + aoff + 64 * 1024 + (kk), &As[buf][2048 + tid * 8]); \
    gl_lds16(Wb + boff + (kk),             &Bs[buf][tid * 8]); \
    gl_lds16(Wb + boff + 64 * 1024 + (kk), &Bs[buf][2048 + tid * 8]); }

    STAGE(0, 0)
    __syncthreads();
    int cur = 0;
    for (int k0 = 0; k0 < 1024; k0 += 32) {
        if (k0 + 32 < 1024) STAGE(cur ^ 1, k0 + 32)
        short8 af[4], bfr[4];
#pragma unroll
        for (int mi = 0; mi < 4; ++mi)
            af[mi] = *(const short8*)&As[cur][(wr * 64 + mi * 16 + lr) * 32 + lg * 8];
#pragma unroll
        for (int ni = 0; ni < 4; ++ni)
            bfr[ni] = *(const short8*)&Bs[cur][(wc * 64 + ni * 16 + lr) * 32 + lg * 8];
#pragma unroll
        for (int mi = 0; mi < 4; ++mi)
#pragma unroll
            for (int ni = 0; ni < 4; ++ni)
                acc[mi][ni] = __builtin_amdgcn_mfma_f32_16x16x32_bf16(af[mi], bfr[ni], acc[mi][ni], 0, 0, 0);
        __syncthreads();
        cur ^= 1;
    }
#undef STAGE

#pragma unroll
    for (int mi = 0; mi < 4; ++mi) {
#pragma unroll
        for (int ni = 0; ni < 4; ++ni) {
            const int n = bn * 128 + wc * 64 + ni * 16 + lr;
#pragma unroll
            for (int i = 0; i < 4; ++i) {
                const int m = bm * 128 + wr * 64 + mi * 16 + lg * 4 + i;
                Cp[(size_t)m * 1024 + n] = acc[mi][ni][i] + bias[n];
            }
        }
    }
}

// ---------------- flash attention (r15 version: reg-staged dbuf, padded LDS) ----------------
// grid (S/128, B*H), 256 threads. Wave w owns q rows qw..qw+31.
// DOUBLE-BUFFERED K/V LDS (36.9 KB), ONE barrier per tile:
//   { write prefetched tile t -> buf[t&1]; issue loads t+1; barrier; compute t }
// q (pre-scaled by log2e via Wq), k: [B,H,S,D] bf16. vtt: [B,H,S/64,D,64] bf16.
//   S^T = mfma(K,Q): C col = q = lane&31, row = kv = (reg&3)+8*(reg>>2)+4*(lane>>5)
// P = 2^(s-64) fixed-shift softmax; PV B-operand in-register via cvt_pk + permlane32.
__global__ __launch_bounds__(256, 4) void attn_kernel(const unsigned short* __restrict__ q,
                                                      const unsigned short* __restrict__ k,
                                                      const unsigned short* __restrict__ vtt,
                                                      unsigned short* __restrict__ o) {
    __shared__ unsigned short Kl[2][64][72];  // [buf][kv][d]
    __shared__ unsigned short Vl[2][64][72];  // [buf][d][kv]
    const int tid = threadIdx.x;
    const int lane = tid & 63, wid = tid >> 6;
    const int l31 = lane & 31, hi = lane >> 5;
    const int bh = blockIdx.y;
    const int qw = blockIdx.x * 128 + wid * 32;   // this wave's first q row
    const size_t base = (size_t)bh * NS * ND;     // same stride for q/k and vtt

    // Q fragments (B-operand): col = q = l31, k = d = 16m + 8*hi + j
    short8 qf[4];
    {
        const unsigned short* qp = q + base + (size_t)(qw + l31) * ND + 8 * hi;
#pragma unroll
        for (int m = 0; m < 4; ++m) qf[m] = *(const short8*)(qp + 16 * m);
    }

    float l_run = 0.f;                        // softmax denom (x 2^-64) for q-row l31
    f32x16 oa0, oa1, fz;
#pragma unroll
    for (int i = 0; i < 16; ++i) { oa0[i] = 0.f; oa1[i] = 0.f; fz[i] = 0.f; }

    // staging: 8KB tile / 256 threads = 32B per thread, contiguous
    const int strow = tid >> 2, stcol = (tid & 3) * 16;
    const unsigned short* ks = k   + base + tid * 16;   // + t*4096 per tile
    const unsigned short* vs = vtt + base + tid * 16;

    // prologue: prefetch tile 0 into regs (T14)
    short8 kr0 = *(const short8*)(ks);
    short8 kr1 = *(const short8*)(ks + 8);
    short8 vr0 = *(const short8*)(vs);
    short8 vr1 = *(const short8*)(vs + 8);

    for (int t = 0; t < NS / 64; ++t) {
        const int buf = t & 1;
        // write prefetched tile t (vmcnt wait for loads issued at t-1 lands here)
        *(short8*)&Kl[buf][strow][stcol]     = kr0;
        *(short8*)&Kl[buf][strow][stcol + 8] = kr1;
        *(short8*)&Vl[buf][strow][stcol]     = vr0;
        *(short8*)&Vl[buf][strow][stcol + 8] = vr1;

        // issue next tile's loads; they fly under this tile's compute
        if (t + 1 < NS / 64) {
            const unsigned short* ks2 = ks + (size_t)(t + 1) * 64 * ND;
            const unsigned short* vs2 = vs + (size_t)(t + 1) * 64 * ND;
            kr0 = *(const short8*)(ks2);
            kr1 = *(const short8*)(ks2 + 8);
            vr0 = *(const short8*)(vs2);
            vr1 = *(const short8*)(vs2 + 8);
        }

        __syncthreads();   // tile t visible to all waves

        // S^T = K·Q^T: two 32-kv subtiles, K=64 via 4 chained mfma each
        f32x16 st0, st1;
        __builtin_amdgcn_s_setprio(1);
        {
            short8 kf;
            kf = *(const short8*)&Kl[buf][l31][8 * hi];
            st0 = __builtin_amdgcn_mfma_f32_32x32x16_bf16(kf, qf[0], fz, 0, 0, 0);
            kf = *(const short8*)&Kl[buf][l31][16 + 8 * hi];
            st0 = __builtin_amdgcn_mfma_f32_32x32x16_bf16(kf, qf[1], st0, 0, 0, 0);
            kf = *(const short8*)&Kl[buf][l31][32 + 8 * hi];
            st0 = __builtin_amdgcn_mfma_f32_32x32x16_bf16(kf, qf[2], st0, 0, 0, 0);
            kf = *(const short8*)&Kl[buf][l31][48 + 8 * hi];
            st0 = __builtin_amdgcn_mfma_f32_32x32x16_bf16(kf, qf[3], st0, 0, 0, 0);
            kf = *(const short8*)&Kl[buf][32 + l31][8 * hi];
            st1 = __builtin_amdgcn_mfma_f32_32x32x16_bf16(kf, qf[0], fz, 0, 0, 0);
            kf = *(const short8*)&Kl[buf][32 + l31][16 + 8 * hi];
            st1 = __builtin_amdgcn_mfma_f32_32x32x16_bf16(kf, qf[1], st1, 0, 0, 0);
            kf = *(const short8*)&Kl[buf][32 + l31][32 + 8 * hi];
            st1 = __builtin_amdgcn_mfma_f32_32x32x16_bf16(kf, qf[2], st1, 0, 0, 0);
            kf = *(const short8*)&Kl[buf][32 + l31][48 + 8 * hi];
            st1 = __builtin_amdgcn_mfma_f32_32x32x16_bf16(kf, qf[3], st1, 0, 0, 0);
        }
        __builtin_amdgcn_s_setprio(0);

        // P = 2^(s - 64): packed subtract + native v_exp (1 op/elem; no max tracking)
        st0 = st0 - 64.0f;
        st1 = st1 - 64.0f;
#pragma unroll
        for (int i = 0; i < 16; ++i) st0[i] = exp2n(st0[i]);
#pragma unroll
        for (int i = 0; i < 16; ++i) st1[i] = exp2n(st1[i]);
        {   // packed tree sum of 32 exps -> denom
            f32x16 sv = st0 + st1;
            f32x8 s8 = __builtin_shufflevector(sv, sv, 0, 1, 2, 3, 4, 5, 6, 7)
                     + __builtin_shufflevector(sv, sv, 8, 9, 10, 11, 12, 13, 14, 15);
            f32x4 s4 = __builtin_shufflevector(s8, s8, 0, 1, 2, 3)
                     + __builtin_shufflevector(s8, s8, 4, 5, 6, 7);
            f32x2 s2 = __builtin_shufflevector(s4, s4, 0, 1)
                     + __builtin_shufflevector(s4, s4, 2, 3);
            float rs = s2[0] + s2[1];
            rs += __shfl_xor(rs, 32, 64);
            l_run += rs;
        }

        // P -> PV B-operand fragments, fully in-register (T12)
        short8 pf0, pf1, pf2, pf3;
#define MKPF(PF, SV, RB) { \
        unsigned int wa = packbf(SV[RB + 0], SV[RB + 1]); \
        unsigned int wb = packbf(SV[RB + 2], SV[RB + 3]); \
        unsigned int wc = packbf(SV[RB + 4], SV[RB + 5]); \
        unsigned int wd = packbf(SV[RB + 6], SV[RB + 7]); \
        asm("v_permlane32_swap_b32 %0, %1" : "+v"(wa), "+v"(wc)); \
        asm("v_permlane32_swap_b32 %0, %1" : "+v"(wb), "+v"(wd)); \
        u32x4 pw; pw[0] = wa; pw[1] = wb; pw[2] = wc; pw[3] = wd; \
        PF = __builtin_bit_cast(short8, pw); }
        MKPF(pf0, st0, 0)   // kv  0..15
        MKPF(pf1, st0, 8)   // kv 16..31
        MKPF(pf2, st1, 0)   // kv 32..47
        MKPF(pf3, st1, 8)   // kv 48..63
#undef MKPF

        // O^T += V^T · P^T  (A row = d, B col = q)
        __builtin_amdgcn_s_setprio(1);
        {
            short8 vf;
            vf = *(const short8*)&Vl[buf][l31][8 * hi];
            oa0 = __builtin_amdgcn_mfma_f32_32x32x16_bf16(vf, pf0, oa0, 0, 0, 0);
            vf = *(const short8*)&Vl[buf][l31][16 + 8 * hi];
            oa0 = __builtin_amdgcn_mfma_f32_32x32x16_bf16(vf, pf1, oa0, 0, 0, 0);
            vf = *(const short8*)&Vl[buf][l31][32 + 8 * hi];
            oa0 = __builtin_amdgcn_mfma_f32_32x32x16_bf16(vf, pf2, oa0, 0, 0, 0);
            vf = *(const short8*)&Vl[buf][l31][48 + 8 * hi];
            oa0 = __builtin_amdgcn_mfma_f32_32x32x16_bf16(vf, pf3, oa0, 0, 0, 0);
            vf = *(const short8*)&Vl[buf][32 + l31][8 * hi];
            oa1 = __builtin_amdgcn_mfma_f32_32x32x16_bf16(vf, pf0, oa1, 0, 0, 0);
            vf = *(const short8*)&Vl[buf][32 + l31][16 + 8 * hi];
            oa1 = __builtin_amdgcn_mfma_f32_32x32x16_bf16(vf, pf1, oa1, 0, 0, 0);
            vf = *(const short8*)&Vl[buf][32 + l31][32 + 8 * hi];
            oa1 = __builtin_amdgcn_mfma_f32_32x32x16_bf16(vf, pf2, oa1, 0, 0, 0);
            vf = *(const short8*)&Vl[buf][32 + l31][48 + 8 * hi];
            oa1 = __builtin_amdgcn_mfma_f32_32x32x16_bf16(vf, pf3, oa1, 0, 0, 0);
        }
        __builtin_amdgcn_s_setprio(0);
    }

    // epilogue: C reg r -> d = 32*t + 8*(r>>2) + 4*hi + (r&3); s = qw + l31
    const int b = bh >> 4, h = bh & 15;
    const float scl = 0.125f / l_run;   // softmax BEFORE scaling -> /8 here
    unsigned short* op = o + (((size_t)b * NS + (qw + l31)) * NH + h) * ND;
#pragma unroll
    for (int rq = 0; rq < 4; ++rq) {
        us4 p0, p1;
#pragma unroll
        for (int i = 0; i < 4; ++i) {
            p0[i] = f2bf(oa0[4 * rq + i] * scl);
            p1[i] = f2bf(oa1[4 * rq + i] * scl);
        }
        *(us4*)&op[8 * rq + 4 * hi]      = p0;
        *(us4*)&op[32 + 8 * rq + 4 * hi] = p1;
    }
}

extern "C" void kernel_launch(void* const* d_in, const int* in_sizes, int n_in,
                              void* d_out, int out_size, void* d_ws, size_t ws_size,
                              hipStream_t stream) {
    (void)in_sizes; (void)n_in; (void)out_size; (void)ws_size;
    const float* values  = (const float*)d_in[0];
    const float* keys    = (const float*)d_in[1];
    const float* queries = (const float*)d_in[2];
    const float* Wv = (const float*)d_in[3];
    const float* Wk = (const float*)d_in[4];
    const float* Wq = (const float*)d_in[5];
    const float* Wo = (const float*)d_in[6];
    const float* bo = (const float*)d_in[7];

    uint8_t* ws = (uint8_t*)d_ws;
    const size_t MB = (size_t)1 << 20;
    unsigned short* wvb = (unsigned short*)(ws + 0 * MB);
    unsigned short* wkb = (unsigned short*)(ws + 2 * MB);
    unsigned short* wqb = (unsigned short*)(ws + 4 * MB);
    unsigned short* wob = (unsigned short*)(ws + 6 * MB);
    unsigned short* qb  = (unsigned short*)(ws + 8 * MB);   // [B,H,S,D] bf16 (log2e-scaled)
    unsigned short* kb  = (unsigned short*)(ws + 24 * MB);  // [B,H,S,D] bf16
    unsigned short* vtb = (unsigned short*)(ws + 40 * MB);  // [B,H,S/64,D,64] bf16 (V^T kv-blocked)
    unsigned short* ab  = (unsigned short*)(ws + 56 * MB);  // [B,S,H,D] bf16 (attn out)

    cvt_w4_kernel<<<4096, 256, 0, stream>>>(Wv, Wk, Wq, Wo, wvb, wkb, wqb, wob);

    HybArgs hq;
    hq.a0 = queries; hq.a1 = keys; hq.a2 = values;
    hq.w0 = wqb;     hq.w1 = wkb; hq.w2 = wvb;
    hq.c0 = qb;      hq.c1 = kb;  hq.c2 = vtb;
    gemm_hyb<<<dim3(64, 8, 3), 256, 0, stream>>>(hq);

    attn_kernel<<<dim3(16, 64), 256, 0, stream>>>(qb, kb, vtb, ab);

    gemm_glds<<<dim3(64, 8), 256, 0, stream>>>(ab, wob, (float*)d_out, bo);
}